// Round 1
// baseline (139.927 us; speedup 1.0000x reference)
//
#include <hip/hip_runtime.h>

// Problem constants
#define NNODES 64
#define HID 32
#define NFACT 3
#define NE 1024
#define NROWS (NE + NFACT)   // 1027
#define TPB 512              // R14: 8 waves/graph (was 4). Grid=1024 blocks is
                             // exactly 4 blocks/CU; at TPB=256 that capped the
                             // CU at 16 waves (50% occ, measured 34%). TPB=512
                             // fills all 32 wave slots: 4x39936B LDS = 156KB
                             // <= 160KB, VGPR 56 <= 64 so 8 waves/SIMD legal.
#define STR 36               // float row stride for xpp and P-phase qp
#define QSTRH 20             // u32 row stride for bf16 Q-phase qp (16 data + 4 pad)
#define MAXTILES 128         // 16-edge tile capacity (true max = 124)
#define EPT (NE / TPB)       // 2 edges cached per thread

typedef short bf16x8 __attribute__((ext_vector_type(8)));
typedef float f32x4  __attribute__((ext_vector_type(4)));
typedef float f32x16 __attribute__((ext_vector_type(16)));

// round-to-nearest-even two fp32 -> packed bf16x2 (lo | hi<<16)
__device__ __forceinline__ unsigned pack_bf2(float lo, float hi) {
    unsigned ul = __builtin_bit_cast(unsigned, lo);
    unsigned uh = __builtin_bit_cast(unsigned, hi);
    ul += 0x7fffu + ((ul >> 16) & 1u);
    uh += 0x7fffu + ((uh >> 16) & 1u);
    return (ul >> 16) | (uh & 0xffff0000u);
}
__device__ __forceinline__ short f2bf(float f) {
    unsigned u = __builtin_bit_cast(unsigned, f);
    u += 0x7fffu + ((u >> 16) & 1u);
    return (short)(u >> 16);
}
// unpack halves of a packed bf16x2 to fp32
__device__ __forceinline__ float bflo(unsigned u) { return __builtin_bit_cast(float, u << 16); }
__device__ __forceinline__ float bfhi(unsigned u) { return __builtin_bit_cast(float, u & 0xffff0000u); }
__device__ __forceinline__ float4 fma4(float a, float4 w, float4 c) {
    c.x = fmaf(a, w.x, c.x); c.y = fmaf(a, w.y, c.y);
    c.z = fmaf(a, w.z, c.z); c.w = fmaf(a, w.w, c.w);
    return c;
}

// R12 structure + bf16-packed Q storage, re-decomposed over 8 waves (R14):
// waves 0-3 own Q1/P1, waves 4-7 own Q2/P2; stage B strides by 8; EPT=2.
//   pep packed: low12 = edge id (0xFFF = pad), bits12-17 = dst, bits18-23 = src
__global__ __launch_bounds__(TPB, 8) void critic_fused(
    const float* __restrict__ x,
    const float* __restrict__ edge_attr,
    const float* __restrict__ action,
    const int*   __restrict__ es,
    const int*   __restrict__ ed,
    const float* __restrict__ W1,
    const float* __restrict__ b1,
    const float* __restrict__ W2,
    const float* __restrict__ b2,
    const float* __restrict__ Wl,
    const float* __restrict__ bl,
    const float* __restrict__ Wv,
    const float* __restrict__ bv,
    float* __restrict__ out)
{
    const int b    = blockIdx.x;
    const int tid  = threadIdx.x;
    const int lane = tid & 63;
    const int wv   = tid >> 6;          // 0..7
    const int quad = lane >> 4;
    const int m16  = lane & 15;
    const int kh   = quad * 8;

    __shared__ __align__(16) float4 xs4[NNODES];
    __shared__ __align__(16) float  xpp[NNODES * STR];
    __shared__ __align__(16) float  qp0[NNODES * STR];   // bf16 Q1 (u32 view) then fp32 P1
    __shared__ __align__(16) float  qp1[NNODES * STR];   // bf16 Q2 (u32 view) then fp32 P2
    __shared__ __align__(16) float  W1s[10 * HID];
    __shared__ float  b1s[HID];
    __shared__ float  wred[TPB / 64];
    // CSR tables (built per block, 16-edge tiles)
    __shared__ int    sdeg[NNODES], soff[NNODES], scnt[NNODES];
    __shared__ int    tns[MAXTILES];
    __shared__ int    pep[MAXTILES * 16];
    __shared__ int    snt;

    unsigned* qh0 = (unsigned*)qp0;   // bf16 Q rows: stride QSTRH u32
    unsigned* qh1 = (unsigned*)qp1;

    // ---- Stage A: stage x + W1, zero xpp, init CSR tables ----
    if (tid < NNODES) { xs4[tid] = ((const float4*)x)[b * NNODES + tid]; sdeg[tid] = 0; scnt[tid] = 0; }
    if (tid < 80) ((float4*)W1s)[tid] = ((const float4*)W1)[tid];
    if (tid < HID) b1s[tid] = b1[tid];
    if (tid < MAXTILES) tns[tid] = 0;
#pragma unroll
    for (int i = 0; i < MAXTILES * 16 / TPB; i++) pep[tid + i * TPB] = 0xFFF;  // pad, node 0
    {   // vectorized xpp zero: 2304 floats = 576 float4 slots
        const float4 z4 = make_float4(0.f, 0.f, 0.f, 0.f);
#pragma unroll 1
        for (int i = tid; i < NNODES * STR / 4; i += TPB) ((float4*)xpp)[i] = z4;
    }

    // cache this thread's 2 edges in registers (coalesced global reads)
    int ces[EPT], ced[EPT];
#pragma unroll
    for (int i = 0; i < EPT; i++) {
        ces[i] = es[tid + i * TPB];
        ced[i] = ed[tid + i * TPB];
    }
    __syncthreads();

    // ---- CSR count + Stage Q (independent; co-scheduled to hide latency) ----
#pragma unroll
    for (int i = 0; i < EPT; i++) atomicAdd(&sdeg[ces[i]], 1);
    {
        // waves 0-3: Q1 (W1 rows 0-3 + b1), waves 4-7: Q2 (W1 rows 4-7)
        const int  n  = lane;
        const int  k0 = (wv & 3) * 8;
        const bool g1 = (wv < 4);
        const int  rb = g1 ? 0 : 4;
        const float4 xv = xs4[n];
        float4 qa, qb;
        if (g1) {
            const float4* b1v = (const float4*)&b1s[k0];
            qa = b1v[0]; qb = b1v[1];
        } else {
            qa = make_float4(0.f, 0.f, 0.f, 0.f); qb = qa;
        }
#pragma unroll 1
        for (int i = 0; i < 4; i++) {
            const float xi = (i == 0) ? xv.x : (i == 1) ? xv.y : (i == 2) ? xv.z : xv.w;
            const float4* wa = (const float4*)&W1s[(rb + i) * HID + k0];
            qa = fma4(xi, wa[0], qa); qb = fma4(xi, wa[1], qb);
        }
        uint4 p;   // pack 8 fp32 -> 4 u32 (bf16 pairs), one b128 write
        p.x = pack_bf2(qa.x, qa.y); p.y = pack_bf2(qa.z, qa.w);
        p.z = pack_bf2(qb.x, qb.y); p.w = pack_bf2(qb.z, qb.w);
        unsigned* dst = g1 ? qh0 : qh1;
        *(uint4*)&dst[n * QSTRH + (wv & 3) * 4] = p;
    }
    __syncthreads();

    // ---- CSR scan (wave 0) + tile-node fill ----
    if (tid < NNODES) {
        const int cnt = (sdeg[tid] + 15) >> 4;
        int scan = cnt;
#pragma unroll
        for (int o = 1; o < 64; o <<= 1) {
            const int v = __shfl_up(scan, o);
            if (tid >= o) scan += v;
        }
        const int base = scan - cnt;
        soff[tid] = base;
        if (tid == NNODES - 1) snt = scan;           // ~90-96, <=124
#pragma unroll 1
        for (int j = 0; j < cnt; j++) tns[base + j] = tid;
    }
    __syncthreads();

    // ---- CSR scatter (cached edges) ----
#pragma unroll
    for (int i = 0; i < EPT; i++) {
        const int n = ces[i];
        const int idx = atomicAdd(&scnt[n], 1);
        pep[soff[n] * 16 + idx] = (tid + i * TPB) | (ced[i] << 12) | (n << 18);
    }
    __syncthreads();

    // ---- Stage B: pair-tiled MFMA edge messages (32 edges / 2 nodes per iteration) ----
    {
        const float2* ea2 = (const float2*)edge_attr + (size_t)b * NE;
        const int NW   = TPB / 64;             // 8 waves
        const int klo  = (lane >> 5) * 8;      // K-slice base (0 or 8)
        const int klo2 = klo >> 1;             // u32 offset of the slice
        const int n32  = lane & 31;

        const float4* w8l = (const float4*)&W1s[8 * HID + klo];
        const float4* w8h = (const float4*)&W1s[8 * HID + 16 + klo];
        const float4* w9l = (const float4*)&W1s[9 * HID + klo];
        const float4* w9h = (const float4*)&W1s[9 * HID + 16 + klo];
        const float4 w8a = w8l[0], w8b = w8l[1], w8c = w8h[0], w8d = w8h[1];
        const float4 w9a = w9l[0], w9b = w9l[1], w9c = w9h[0], w9d = w9h[1];

        bf16x8 bfA, bfB;   // W2 B-frags: B[k][n32], K-halves 0..15 / 16..31
#pragma unroll
        for (int j = 0; j < 8; j++) {
            bfA[j] = f2bf(W2[(klo + j) * HID + n32]);
            bfB[j] = f2bf(W2[(16 + klo + j) * HID + n32]);
        }

        const int np = (snt + 1) >> 1;

#pragma unroll 1
        for (int p = wv; p < np; p += NW) {
            const int raw = pep[p * 32 + n32];        // edge slot = window row n32
            const int tA  = tns[2 * p];
            const int tB  = tns[2 * p + 1];
            const int e    = raw & 0xFFF;
            const bool pad = (e == 0xFFF);
            const int d0   = (raw >> 12) & 63;
            const int nd   = (raw >> 18) & 63;        // src node of MY edge
            const float2 ea = ea2[pad ? 0 : e];

            // bf16-packed gathers: 4 x b128 total (was 8 in fp32)
            const uint4 A1 = *(const uint4*)&qh0[nd * QSTRH + klo2];
            const uint4 A2 = *(const uint4*)&qh0[nd * QSTRH + 8 + klo2];
            const uint4 G1 = *(const uint4*)&qh1[d0 * QSTRH + klo2];
            const uint4 G2 = *(const uint4*)&qh1[d0 * QSTRH + 8 + klo2];

            const float hx0 = fmaxf(bflo(A1.x) + bflo(G1.x) + ea.x * w8a.x + ea.y * w9a.x, 0.f);
            const float hx1 = fmaxf(bfhi(A1.x) + bfhi(G1.x) + ea.x * w8a.y + ea.y * w9a.y, 0.f);
            const float hx2 = fmaxf(bflo(A1.y) + bflo(G1.y) + ea.x * w8a.z + ea.y * w9a.z, 0.f);
            const float hx3 = fmaxf(bfhi(A1.y) + bfhi(G1.y) + ea.x * w8a.w + ea.y * w9a.w, 0.f);
            const float hx4 = fmaxf(bflo(A1.z) + bflo(G1.z) + ea.x * w8b.x + ea.y * w9b.x, 0.f);
            const float hx5 = fmaxf(bfhi(A1.z) + bfhi(G1.z) + ea.x * w8b.y + ea.y * w9b.y, 0.f);
            const float hx6 = fmaxf(bflo(A1.w) + bflo(G1.w) + ea.x * w8b.z + ea.y * w9b.z, 0.f);
            const float hx7 = fmaxf(bfhi(A1.w) + bfhi(G1.w) + ea.x * w8b.w + ea.y * w9b.w, 0.f);
            const float hy0 = fmaxf(bflo(A2.x) + bflo(G2.x) + ea.x * w8c.x + ea.y * w9c.x, 0.f);
            const float hy1 = fmaxf(bfhi(A2.x) + bfhi(G2.x) + ea.x * w8c.y + ea.y * w9c.y, 0.f);
            const float hy2 = fmaxf(bflo(A2.y) + bflo(G2.y) + ea.x * w8c.z + ea.y * w9c.z, 0.f);
            const float hy3 = fmaxf(bfhi(A2.y) + bfhi(G2.y) + ea.x * w8c.w + ea.y * w9c.w, 0.f);
            const float hy4 = fmaxf(bflo(A2.z) + bflo(G2.z) + ea.x * w8d.x + ea.y * w9d.x, 0.f);
            const float hy5 = fmaxf(bfhi(A2.z) + bfhi(G2.z) + ea.x * w8d.y + ea.y * w9d.y, 0.f);
            const float hy6 = fmaxf(bflo(A2.w) + bflo(G2.w) + ea.x * w8d.z + ea.y * w9d.z, 0.f);
            const float hy7 = fmaxf(bfhi(A2.w) + bfhi(G2.w) + ea.x * w8d.w + ea.y * w9d.w, 0.f);

            uint4 pkA, pkB;
            pkA.x = pad ? 0u : pack_bf2(hx0, hx1);
            pkA.y = pad ? 0u : pack_bf2(hx2, hx3);
            pkA.z = pad ? 0u : pack_bf2(hx4, hx5);
            pkA.w = pad ? 0u : pack_bf2(hx6, hx7);
            pkB.x = pad ? 0u : pack_bf2(hy0, hy1);
            pkB.y = pad ? 0u : pack_bf2(hy2, hy3);
            pkB.z = pad ? 0u : pack_bf2(hy4, hy5);
            pkB.w = pad ? 0u : pack_bf2(hy6, hy7);
            const bf16x8 afA = __builtin_bit_cast(bf16x8, pkA);
            const bf16x8 afB = __builtin_bit_cast(bf16x8, pkB);

            f32x16 c;
#pragma unroll
            for (int j = 0; j < 16; j++) c[j] = 0.0f;
            c = __builtin_amdgcn_mfma_f32_32x32x16_bf16(afA, bfA, c, 0, 0, 0);
            c = __builtin_amdgcn_mfma_f32_32x32x16_bf16(afB, bfB, c, 0, 0, 0);

            // C: col=lane&31, row=(reg&3)+8*(reg>>2)+4*(lane>>5).
            // regs 0-7 -> rows 0-15 (tile A), regs 8-15 -> rows 16-31 (tile B).
            float sA = ((c[0] + c[1]) + (c[2] + c[3])) + ((c[4] + c[5]) + (c[6] + c[7]));
            float sB = ((c[8] + c[9]) + (c[10] + c[11])) + ((c[12] + c[13]) + (c[14] + c[15]));
            sA += __shfl_xor(sA, 32);
            sB += __shfl_xor(sB, 32);
            const int   nst = (lane < 32) ? tA : tB;
            const float sv  = (lane < 32) ? sA : sB;
            atomicAdd(&xpp[nst * STR + n32], sv);     // full wave, contiguous per node
        }
    }
    __syncthreads();

    // ---- Stage-P constants (loaded after B to keep stage-B VGPR peak low) ----
    // waves 0-3 produce P1 (Wl[0:36], +bl), waves 4-7 produce P2 (Wl[36:72])
    const bool g1p   = (wv < 4);
    const int  cbase = g1p ? 4 : 40;     // Wl row offset of the MFMA K=32 part
    const int  xbase = g1p ? 0 : 36;     // Wl row offset of the x-part (K=4 tail)
    bf16x8 bPa, bPb;                     // B-fragments, col halves
#pragma unroll
    for (int j = 0; j < 8; j++) {
        bPa[j] = f2bf(Wl[(cbase + kh + j) * HID + m16]);
        bPb[j] = f2bf(Wl[(cbase + kh + j) * HID + 16 + m16]);
    }
    float wxa[4], wxb[4];                // x-part weights
#pragma unroll
    for (int i = 0; i < 4; i++) {
        wxa[i] = Wl[(xbase + i) * HID + m16];
        wxb[i] = Wl[(xbase + i) * HID + 16 + m16];
    }
    const float bca = g1p ? bl[m16] : 0.f;
    const float bcb = g1p ? bl[16 + m16] : 0.f;
    float b2k[8];
#pragma unroll
    for (int j = 0; j < 8; j++) b2k[j] = b2[kh + j];
    const int   mrow = (wv & 3) * 16 + m16;          // A-row this lane owns in stage P
    const float dn   = (float)sdeg[mrow];

    // ---- Stage P: head projections via MFMA (fp32 outputs into stride-36 layout) ----
    {
        const float4* xr = (const float4*)&xpp[mrow * STR + kh];
        float4 x0 = xr[0], x1 = xr[1];
        x0.x = fmaf(dn, b2k[0], x0.x); x0.y = fmaf(dn, b2k[1], x0.y);
        x0.z = fmaf(dn, b2k[2], x0.z); x0.w = fmaf(dn, b2k[3], x0.w);
        x1.x = fmaf(dn, b2k[4], x1.x); x1.y = fmaf(dn, b2k[5], x1.y);
        x1.z = fmaf(dn, b2k[6], x1.z); x1.w = fmaf(dn, b2k[7], x1.w);
        uint4 packed;
        packed.x = pack_bf2(x0.x, x0.y);
        packed.y = pack_bf2(x0.z, x0.w);
        packed.z = pack_bf2(x1.x, x1.y);
        packed.w = pack_bf2(x1.z, x1.w);
        const bf16x8 af = __builtin_bit_cast(bf16x8, packed);

        f32x4 ca, cb;
#pragma unroll
        for (int r = 0; r < 4; r++) {
            const float4 xv = xs4[(wv & 3) * 16 + quad * 4 + r];
            float a0 = bca, a1 = bcb;
#pragma unroll
            for (int i = 0; i < 4; i++) {
                const float xi = (i == 0) ? xv.x : (i == 1) ? xv.y : (i == 2) ? xv.z : xv.w;
                a0 = fmaf(xi, wxa[i], a0);
                a1 = fmaf(xi, wxb[i], a1);
            }
            ca[r] = a0; cb[r] = a1;
        }
        ca = __builtin_amdgcn_mfma_f32_16x16x32_bf16(af, bPa, ca, 0, 0, 0);
        cb = __builtin_amdgcn_mfma_f32_16x16x32_bf16(af, bPb, cb, 0, 0, 0);

        __syncthreads();   // Q-phase bf16 reads fully drained before fp32 overwrite
        // C layout: row = (wv&3)*16 + quad*4 + r, col = m16 / 16+m16
        float* dst = g1p ? qp0 : qp1;
#pragma unroll
        for (int r = 0; r < 4; r++) {
            const int row = (wv & 3) * 16 + quad * 4 + r;
            dst[row * STR + m16]      = ca[r];
            dst[row * STR + 16 + m16] = cb[r];
        }
    }
    __syncthreads();

    // ---- Stage C: per-row combine + value head ----
    float vsum = 0.0f;
    {
        const float* actb = action + (size_t)b * NROWS;
        const float bvv = bv[0];
        const float* Wl72 = Wl + 72 * HID;   // loop-invariant s_loads, hoisted
#pragma unroll 1
        for (int i = 0; i < EPT; i++) {
            const int na = ces[i], nb = ced[i];           // cached edge endpoints
            const float a = actb[tid + i * TPB];
            const float4* p1v = (const float4*)&qp0[na * STR];
            const float4* p2v = (const float4*)&qp1[nb * STR];
            float v0 = bvv, v1 = 0.0f;
#pragma unroll 1
            for (int q = 0; q < 8; q += 2) {
                const float4 pa0 = p1v[q],     pb0 = p2v[q];
                const float4 pa1 = p1v[q + 1], pb1 = p2v[q + 1];
                const int k = q * 4;
                v0 += fmaxf(pa0.x + pb0.x + a * Wl72[k+0], 0.f) * Wv[k+0];
                v1 += fmaxf(pa0.y + pb0.y + a * Wl72[k+1], 0.f) * Wv[k+1];
                v0 += fmaxf(pa0.z + pb0.z + a * Wl72[k+2], 0.f) * Wv[k+2];
                v1 += fmaxf(pa0.w + pb0.w + a * Wl72[k+3], 0.f) * Wv[k+3];
                v0 += fmaxf(pa1.x + pb1.x + a * Wl72[k+4], 0.f) * Wv[k+4];
                v1 += fmaxf(pa1.y + pb1.y + a * Wl72[k+5], 0.f) * Wv[k+5];
                v0 += fmaxf(pa1.z + pb1.z + a * Wl72[k+6], 0.f) * Wv[k+6];
                v1 += fmaxf(pa1.w + pb1.w + a * Wl72[k+7], 0.f) * Wv[k+7];
            }
            vsum += v0 + v1;
        }
        // factory rows 1024..1026 (na == nb)
        if (tid < NFACT) {
            const int r = NE + tid;
            const int na = NNODES - NFACT + tid;
            const float a = actb[r];
            const float4* p1v = (const float4*)&qp0[na * STR];
            const float4* p2v = (const float4*)&qp1[na * STR];
            float v = bvv;
#pragma unroll 1
            for (int q = 0; q < 8; q++) {
                const float4 pa = p1v[q], pb = p2v[q];
                const int k = q * 4;
                v += fmaxf(pa.x + pb.x + a * Wl72[k+0], 0.f) * Wv[k+0];
                v += fmaxf(pa.y + pb.y + a * Wl72[k+1], 0.f) * Wv[k+1];
                v += fmaxf(pa.z + pb.z + a * Wl72[k+2], 0.f) * Wv[k+2];
                v += fmaxf(pa.w + pb.w + a * Wl72[k+3], 0.f) * Wv[k+3];
            }
            vsum += v;
        }
    }

    // ---- block reduction ----
#pragma unroll
    for (int off = 32; off > 0; off >>= 1)
        vsum += __shfl_down(vsum, off, 64);
    if ((tid & 63) == 0) wred[tid >> 6] = vsum;
    __syncthreads();
    if (tid == 0) {
        float t = 0.0f;
#pragma unroll
        for (int w = 0; w < TPB / 64; w++) t += wred[w];
        out[b] = t;
    }
}

extern "C" void kernel_launch(void* const* d_in, const int* in_sizes, int n_in,
                              void* d_out, int out_size, void* d_ws, size_t ws_size,
                              hipStream_t stream) {
    const float* x         = (const float*)d_in[0];
    const float* edge_attr = (const float*)d_in[2];
    const float* action    = (const float*)d_in[3];
    const int*   es        = (const int*)d_in[4];
    const int*   ed        = (const int*)d_in[5];
    const float* W1        = (const float*)d_in[6];
    const float* b1        = (const float*)d_in[7];
    const float* W2        = (const float*)d_in[8];
    const float* b2        = (const float*)d_in[9];
    const float* Wl        = (const float*)d_in[10];
    const float* bl        = (const float*)d_in[11];
    const float* Wv        = (const float*)d_in[12];
    const float* bv        = (const float*)d_in[13];
    float* out = (float*)d_out;

    critic_fused<<<dim3(out_size), dim3(TPB), 0, stream>>>(
        x, edge_attr, action, es, ed, W1, b1, W2, b2, Wl, bl, Wv, bv, out);
}

// Round 2
// 128.398 us; speedup vs baseline: 1.0898x; 1.0898x over previous
//
#include <hip/hip_runtime.h>

// Problem constants
#define NNODES 64
#define HID 32
#define NFACT 3
#define NE 1024
#define NROWS (NE + NFACT)   // 1027
#define TPB 512              // R14: 8 waves/graph. Grid=1024 blocks = 4/CU; at
                             // TPB=256 LDS capped the CU at 16 waves (50% occ).
// R15: launch_bounds min-waves 8 -> 6. (512,8) capped unified VGPR+AGPR at 64
// (rocprof: VGPR=32 arch + AGPRs) -> massive scratch spills (47MB WRITE_SIZE,
// 54MB FETCH vs ~7MB ideal). (512,6) = 85-reg budget (code wants ~56), still
// 3 blocks/CU = 24 waves/CU = 75% occ cap (LDS 3x39936=117KB <= 160KB).
#define STR 36               // float row stride for xpp and P-phase qp
#define QSTRH 20             // u32 row stride for bf16 Q-phase qp (16 data + 4 pad)
#define MAXTILES 128         // 16-edge tile capacity (true max = 124)
#define EPT (NE / TPB)       // 2 edges cached per thread

typedef short bf16x8 __attribute__((ext_vector_type(8)));
typedef float f32x4  __attribute__((ext_vector_type(4)));
typedef float f32x16 __attribute__((ext_vector_type(16)));

// round-to-nearest-even two fp32 -> packed bf16x2 (lo | hi<<16)
__device__ __forceinline__ unsigned pack_bf2(float lo, float hi) {
    unsigned ul = __builtin_bit_cast(unsigned, lo);
    unsigned uh = __builtin_bit_cast(unsigned, hi);
    ul += 0x7fffu + ((ul >> 16) & 1u);
    uh += 0x7fffu + ((uh >> 16) & 1u);
    return (ul >> 16) | (uh & 0xffff0000u);
}
__device__ __forceinline__ short f2bf(float f) {
    unsigned u = __builtin_bit_cast(unsigned, f);
    u += 0x7fffu + ((u >> 16) & 1u);
    return (short)(u >> 16);
}
// unpack halves of a packed bf16x2 to fp32
__device__ __forceinline__ float bflo(unsigned u) { return __builtin_bit_cast(float, u << 16); }
__device__ __forceinline__ float bfhi(unsigned u) { return __builtin_bit_cast(float, u & 0xffff0000u); }
__device__ __forceinline__ float4 fma4(float a, float4 w, float4 c) {
    c.x = fmaf(a, w.x, c.x); c.y = fmaf(a, w.y, c.y);
    c.z = fmaf(a, w.z, c.z); c.w = fmaf(a, w.w, c.w);
    return c;
}

// R12 structure + bf16-packed Q storage, re-decomposed over 8 waves (R14):
// waves 0-3 own Q1/P1, waves 4-7 own Q2/P2; stage B strides by 8; EPT=2.
//   pep packed: low12 = edge id (0xFFF = pad), bits12-17 = dst, bits18-23 = src
__global__ __launch_bounds__(TPB, 6) void critic_fused(
    const float* __restrict__ x,
    const float* __restrict__ edge_attr,
    const float* __restrict__ action,
    const int*   __restrict__ es,
    const int*   __restrict__ ed,
    const float* __restrict__ W1,
    const float* __restrict__ b1,
    const float* __restrict__ W2,
    const float* __restrict__ b2,
    const float* __restrict__ Wl,
    const float* __restrict__ bl,
    const float* __restrict__ Wv,
    const float* __restrict__ bv,
    float* __restrict__ out)
{
    const int b    = blockIdx.x;
    const int tid  = threadIdx.x;
    const int lane = tid & 63;
    const int wv   = tid >> 6;          // 0..7
    const int quad = lane >> 4;
    const int m16  = lane & 15;
    const int kh   = quad * 8;

    __shared__ __align__(16) float4 xs4[NNODES];
    __shared__ __align__(16) float  xpp[NNODES * STR];
    __shared__ __align__(16) float  qp0[NNODES * STR];   // bf16 Q1 (u32 view) then fp32 P1
    __shared__ __align__(16) float  qp1[NNODES * STR];   // bf16 Q2 (u32 view) then fp32 P2
    __shared__ __align__(16) float  W1s[10 * HID];
    __shared__ float  b1s[HID];
    __shared__ float  wred[TPB / 64];
    // CSR tables (built per block, 16-edge tiles)
    __shared__ int    sdeg[NNODES], soff[NNODES], scnt[NNODES];
    __shared__ int    tns[MAXTILES];
    __shared__ int    pep[MAXTILES * 16];
    __shared__ int    snt;

    unsigned* qh0 = (unsigned*)qp0;   // bf16 Q rows: stride QSTRH u32
    unsigned* qh1 = (unsigned*)qp1;

    // ---- Stage A: stage x + W1, zero xpp, init CSR tables ----
    if (tid < NNODES) { xs4[tid] = ((const float4*)x)[b * NNODES + tid]; sdeg[tid] = 0; scnt[tid] = 0; }
    if (tid < 80) ((float4*)W1s)[tid] = ((const float4*)W1)[tid];
    if (tid < HID) b1s[tid] = b1[tid];
    if (tid < MAXTILES) tns[tid] = 0;
#pragma unroll
    for (int i = 0; i < MAXTILES * 16 / TPB; i++) pep[tid + i * TPB] = 0xFFF;  // pad, node 0
    {   // vectorized xpp zero: 2304 floats = 576 float4 slots
        const float4 z4 = make_float4(0.f, 0.f, 0.f, 0.f);
#pragma unroll 1
        for (int i = tid; i < NNODES * STR / 4; i += TPB) ((float4*)xpp)[i] = z4;
    }

    // cache this thread's 2 edges in registers (coalesced global reads)
    int ces[EPT], ced[EPT];
#pragma unroll
    for (int i = 0; i < EPT; i++) {
        ces[i] = es[tid + i * TPB];
        ced[i] = ed[tid + i * TPB];
    }
    __syncthreads();

    // ---- CSR count + Stage Q (independent; co-scheduled to hide latency) ----
#pragma unroll
    for (int i = 0; i < EPT; i++) atomicAdd(&sdeg[ces[i]], 1);
    {
        // waves 0-3: Q1 (W1 rows 0-3 + b1), waves 4-7: Q2 (W1 rows 4-7)
        const int  n  = lane;
        const int  k0 = (wv & 3) * 8;
        const bool g1 = (wv < 4);
        const int  rb = g1 ? 0 : 4;
        const float4 xv = xs4[n];
        float4 qa, qb;
        if (g1) {
            const float4* b1v = (const float4*)&b1s[k0];
            qa = b1v[0]; qb = b1v[1];
        } else {
            qa = make_float4(0.f, 0.f, 0.f, 0.f); qb = qa;
        }
#pragma unroll 1
        for (int i = 0; i < 4; i++) {
            const float xi = (i == 0) ? xv.x : (i == 1) ? xv.y : (i == 2) ? xv.z : xv.w;
            const float4* wa = (const float4*)&W1s[(rb + i) * HID + k0];
            qa = fma4(xi, wa[0], qa); qb = fma4(xi, wa[1], qb);
        }
        uint4 p;   // pack 8 fp32 -> 4 u32 (bf16 pairs), one b128 write
        p.x = pack_bf2(qa.x, qa.y); p.y = pack_bf2(qa.z, qa.w);
        p.z = pack_bf2(qb.x, qb.y); p.w = pack_bf2(qb.z, qb.w);
        unsigned* dst = g1 ? qh0 : qh1;
        *(uint4*)&dst[n * QSTRH + (wv & 3) * 4] = p;
    }
    __syncthreads();

    // ---- CSR scan (wave 0) + tile-node fill ----
    if (tid < NNODES) {
        const int cnt = (sdeg[tid] + 15) >> 4;
        int scan = cnt;
#pragma unroll
        for (int o = 1; o < 64; o <<= 1) {
            const int v = __shfl_up(scan, o);
            if (tid >= o) scan += v;
        }
        const int base = scan - cnt;
        soff[tid] = base;
        if (tid == NNODES - 1) snt = scan;           // ~90-96, <=124
#pragma unroll 1
        for (int j = 0; j < cnt; j++) tns[base + j] = tid;
    }
    __syncthreads();

    // ---- CSR scatter (cached edges) ----
#pragma unroll
    for (int i = 0; i < EPT; i++) {
        const int n = ces[i];
        const int idx = atomicAdd(&scnt[n], 1);
        pep[soff[n] * 16 + idx] = (tid + i * TPB) | (ced[i] << 12) | (n << 18);
    }
    __syncthreads();

    // ---- Stage B: pair-tiled MFMA edge messages (32 edges / 2 nodes per iteration) ----
    {
        const float2* ea2 = (const float2*)edge_attr + (size_t)b * NE;
        const int NW   = TPB / 64;             // 8 waves
        const int klo  = (lane >> 5) * 8;      // K-slice base (0 or 8)
        const int klo2 = klo >> 1;             // u32 offset of the slice
        const int n32  = lane & 31;

        const float4* w8l = (const float4*)&W1s[8 * HID + klo];
        const float4* w8h = (const float4*)&W1s[8 * HID + 16 + klo];
        const float4* w9l = (const float4*)&W1s[9 * HID + klo];
        const float4* w9h = (const float4*)&W1s[9 * HID + 16 + klo];
        const float4 w8a = w8l[0], w8b = w8l[1], w8c = w8h[0], w8d = w8h[1];
        const float4 w9a = w9l[0], w9b = w9l[1], w9c = w9h[0], w9d = w9h[1];

        bf16x8 bfA, bfB;   // W2 B-frags: B[k][n32], K-halves 0..15 / 16..31
#pragma unroll
        for (int j = 0; j < 8; j++) {
            bfA[j] = f2bf(W2[(klo + j) * HID + n32]);
            bfB[j] = f2bf(W2[(16 + klo + j) * HID + n32]);
        }

        const int np = (snt + 1) >> 1;

#pragma unroll 1
        for (int p = wv; p < np; p += NW) {
            const int raw = pep[p * 32 + n32];        // edge slot = window row n32
            const int tA  = tns[2 * p];
            const int tB  = tns[2 * p + 1];
            const int e    = raw & 0xFFF;
            const bool pad = (e == 0xFFF);
            const int d0   = (raw >> 12) & 63;
            const int nd   = (raw >> 18) & 63;        // src node of MY edge
            const float2 ea = ea2[pad ? 0 : e];

            // bf16-packed gathers: 4 x b128 total (was 8 in fp32)
            const uint4 A1 = *(const uint4*)&qh0[nd * QSTRH + klo2];
            const uint4 A2 = *(const uint4*)&qh0[nd * QSTRH + 8 + klo2];
            const uint4 G1 = *(const uint4*)&qh1[d0 * QSTRH + klo2];
            const uint4 G2 = *(const uint4*)&qh1[d0 * QSTRH + 8 + klo2];

            const float hx0 = fmaxf(bflo(A1.x) + bflo(G1.x) + ea.x * w8a.x + ea.y * w9a.x, 0.f);
            const float hx1 = fmaxf(bfhi(A1.x) + bfhi(G1.x) + ea.x * w8a.y + ea.y * w9a.y, 0.f);
            const float hx2 = fmaxf(bflo(A1.y) + bflo(G1.y) + ea.x * w8a.z + ea.y * w9a.z, 0.f);
            const float hx3 = fmaxf(bfhi(A1.y) + bfhi(G1.y) + ea.x * w8a.w + ea.y * w9a.w, 0.f);
            const float hx4 = fmaxf(bflo(A1.z) + bflo(G1.z) + ea.x * w8b.x + ea.y * w9b.x, 0.f);
            const float hx5 = fmaxf(bfhi(A1.z) + bfhi(G1.z) + ea.x * w8b.y + ea.y * w9b.y, 0.f);
            const float hx6 = fmaxf(bflo(A1.w) + bflo(G1.w) + ea.x * w8b.z + ea.y * w9b.z, 0.f);
            const float hx7 = fmaxf(bfhi(A1.w) + bfhi(G1.w) + ea.x * w8b.w + ea.y * w9b.w, 0.f);
            const float hy0 = fmaxf(bflo(A2.x) + bflo(G2.x) + ea.x * w8c.x + ea.y * w9c.x, 0.f);
            const float hy1 = fmaxf(bfhi(A2.x) + bfhi(G2.x) + ea.x * w8c.y + ea.y * w9c.y, 0.f);
            const float hy2 = fmaxf(bflo(A2.y) + bflo(G2.y) + ea.x * w8c.z + ea.y * w9c.z, 0.f);
            const float hy3 = fmaxf(bfhi(A2.y) + bfhi(G2.y) + ea.x * w8c.w + ea.y * w9c.w, 0.f);
            const float hy4 = fmaxf(bflo(A2.z) + bflo(G2.z) + ea.x * w8d.x + ea.y * w9d.x, 0.f);
            const float hy5 = fmaxf(bfhi(A2.z) + bfhi(G2.z) + ea.x * w8d.y + ea.y * w9d.y, 0.f);
            const float hy6 = fmaxf(bflo(A2.w) + bflo(G2.w) + ea.x * w8d.z + ea.y * w9d.z, 0.f);
            const float hy7 = fmaxf(bfhi(A2.w) + bfhi(G2.w) + ea.x * w8d.w + ea.y * w9d.w, 0.f);

            uint4 pkA, pkB;
            pkA.x = pad ? 0u : pack_bf2(hx0, hx1);
            pkA.y = pad ? 0u : pack_bf2(hx2, hx3);
            pkA.z = pad ? 0u : pack_bf2(hx4, hx5);
            pkA.w = pad ? 0u : pack_bf2(hx6, hx7);
            pkB.x = pad ? 0u : pack_bf2(hy0, hy1);
            pkB.y = pad ? 0u : pack_bf2(hy2, hy3);
            pkB.z = pad ? 0u : pack_bf2(hy4, hy5);
            pkB.w = pad ? 0u : pack_bf2(hy6, hy7);
            const bf16x8 afA = __builtin_bit_cast(bf16x8, pkA);
            const bf16x8 afB = __builtin_bit_cast(bf16x8, pkB);

            f32x16 c;
#pragma unroll
            for (int j = 0; j < 16; j++) c[j] = 0.0f;
            c = __builtin_amdgcn_mfma_f32_32x32x16_bf16(afA, bfA, c, 0, 0, 0);
            c = __builtin_amdgcn_mfma_f32_32x32x16_bf16(afB, bfB, c, 0, 0, 0);

            // C: col=lane&31, row=(reg&3)+8*(reg>>2)+4*(lane>>5).
            // regs 0-7 -> rows 0-15 (tile A), regs 8-15 -> rows 16-31 (tile B).
            float sA = ((c[0] + c[1]) + (c[2] + c[3])) + ((c[4] + c[5]) + (c[6] + c[7]));
            float sB = ((c[8] + c[9]) + (c[10] + c[11])) + ((c[12] + c[13]) + (c[14] + c[15]));
            sA += __shfl_xor(sA, 32);
            sB += __shfl_xor(sB, 32);
            const int   nst = (lane < 32) ? tA : tB;
            const float sv  = (lane < 32) ? sA : sB;
            atomicAdd(&xpp[nst * STR + n32], sv);     // full wave, contiguous per node
        }
    }
    __syncthreads();

    // ---- Stage-P constants (loaded after B to keep stage-B VGPR peak low) ----
    // waves 0-3 produce P1 (Wl[0:36], +bl), waves 4-7 produce P2 (Wl[36:72])
    const bool g1p   = (wv < 4);
    const int  cbase = g1p ? 4 : 40;     // Wl row offset of the MFMA K=32 part
    const int  xbase = g1p ? 0 : 36;     // Wl row offset of the x-part (K=4 tail)
    bf16x8 bPa, bPb;                     // B-fragments, col halves
#pragma unroll
    for (int j = 0; j < 8; j++) {
        bPa[j] = f2bf(Wl[(cbase + kh + j) * HID + m16]);
        bPb[j] = f2bf(Wl[(cbase + kh + j) * HID + 16 + m16]);
    }
    float wxa[4], wxb[4];                // x-part weights
#pragma unroll
    for (int i = 0; i < 4; i++) {
        wxa[i] = Wl[(xbase + i) * HID + m16];
        wxb[i] = Wl[(xbase + i) * HID + 16 + m16];
    }
    const float bca = g1p ? bl[m16] : 0.f;
    const float bcb = g1p ? bl[16 + m16] : 0.f;
    float b2k[8];
#pragma unroll
    for (int j = 0; j < 8; j++) b2k[j] = b2[kh + j];
    const int   mrow = (wv & 3) * 16 + m16;          // A-row this lane owns in stage P
    const float dn   = (float)sdeg[mrow];

    // ---- Stage P: head projections via MFMA (fp32 outputs into stride-36 layout) ----
    {
        const float4* xr = (const float4*)&xpp[mrow * STR + kh];
        float4 x0 = xr[0], x1 = xr[1];
        x0.x = fmaf(dn, b2k[0], x0.x); x0.y = fmaf(dn, b2k[1], x0.y);
        x0.z = fmaf(dn, b2k[2], x0.z); x0.w = fmaf(dn, b2k[3], x0.w);
        x1.x = fmaf(dn, b2k[4], x1.x); x1.y = fmaf(dn, b2k[5], x1.y);
        x1.z = fmaf(dn, b2k[6], x1.z); x1.w = fmaf(dn, b2k[7], x1.w);
        uint4 packed;
        packed.x = pack_bf2(x0.x, x0.y);
        packed.y = pack_bf2(x0.z, x0.w);
        packed.z = pack_bf2(x1.x, x1.y);
        packed.w = pack_bf2(x1.z, x1.w);
        const bf16x8 af = __builtin_bit_cast(bf16x8, packed);

        f32x4 ca, cb;
#pragma unroll
        for (int r = 0; r < 4; r++) {
            const float4 xv = xs4[(wv & 3) * 16 + quad * 4 + r];
            float a0 = bca, a1 = bcb;
#pragma unroll
            for (int i = 0; i < 4; i++) {
                const float xi = (i == 0) ? xv.x : (i == 1) ? xv.y : (i == 2) ? xv.z : xv.w;
                a0 = fmaf(xi, wxa[i], a0);
                a1 = fmaf(xi, wxb[i], a1);
            }
            ca[r] = a0; cb[r] = a1;
        }
        ca = __builtin_amdgcn_mfma_f32_16x16x32_bf16(af, bPa, ca, 0, 0, 0);
        cb = __builtin_amdgcn_mfma_f32_16x16x32_bf16(af, bPb, cb, 0, 0, 0);

        __syncthreads();   // Q-phase bf16 reads fully drained before fp32 overwrite
        // C layout: row = (wv&3)*16 + quad*4 + r, col = m16 / 16+m16
        float* dst = g1p ? qp0 : qp1;
#pragma unroll
        for (int r = 0; r < 4; r++) {
            const int row = (wv & 3) * 16 + quad * 4 + r;
            dst[row * STR + m16]      = ca[r];
            dst[row * STR + 16 + m16] = cb[r];
        }
    }
    __syncthreads();

    // ---- Stage C: per-row combine + value head ----
    float vsum = 0.0f;
    {
        const float* actb = action + (size_t)b * NROWS;
        const float bvv = bv[0];
        const float* Wl72 = Wl + 72 * HID;   // loop-invariant s_loads, hoisted
#pragma unroll 1
        for (int i = 0; i < EPT; i++) {
            const int na = ces[i], nb = ced[i];           // cached edge endpoints
            const float a = actb[tid + i * TPB];
            const float4* p1v = (const float4*)&qp0[na * STR];
            const float4* p2v = (const float4*)&qp1[nb * STR];
            float v0 = bvv, v1 = 0.0f;
#pragma unroll 1
            for (int q = 0; q < 8; q += 2) {
                const float4 pa0 = p1v[q],     pb0 = p2v[q];
                const float4 pa1 = p1v[q + 1], pb1 = p2v[q + 1];
                const int k = q * 4;
                v0 += fmaxf(pa0.x + pb0.x + a * Wl72[k+0], 0.f) * Wv[k+0];
                v1 += fmaxf(pa0.y + pb0.y + a * Wl72[k+1], 0.f) * Wv[k+1];
                v0 += fmaxf(pa0.z + pb0.z + a * Wl72[k+2], 0.f) * Wv[k+2];
                v1 += fmaxf(pa0.w + pb0.w + a * Wl72[k+3], 0.f) * Wv[k+3];
                v0 += fmaxf(pa1.x + pb1.x + a * Wl72[k+4], 0.f) * Wv[k+4];
                v1 += fmaxf(pa1.y + pb1.y + a * Wl72[k+5], 0.f) * Wv[k+5];
                v0 += fmaxf(pa1.z + pb1.z + a * Wl72[k+6], 0.f) * Wv[k+6];
                v1 += fmaxf(pa1.w + pb1.w + a * Wl72[k+7], 0.f) * Wv[k+7];
            }
            vsum += v0 + v1;
        }
        // factory rows 1024..1026 (na == nb)
        if (tid < NFACT) {
            const int r = NE + tid;
            const int na = NNODES - NFACT + tid;
            const float a = actb[r];
            const float4* p1v = (const float4*)&qp0[na * STR];
            const float4* p2v = (const float4*)&qp1[na * STR];
            float v = bvv;
#pragma unroll 1
            for (int q = 0; q < 8; q++) {
                const float4 pa = p1v[q], pb = p2v[q];
                const int k = q * 4;
                v += fmaxf(pa.x + pb.x + a * Wl72[k+0], 0.f) * Wv[k+0];
                v += fmaxf(pa.y + pb.y + a * Wl72[k+1], 0.f) * Wv[k+1];
                v += fmaxf(pa.z + pb.z + a * Wl72[k+2], 0.f) * Wv[k+2];
                v += fmaxf(pa.w + pb.w + a * Wl72[k+3], 0.f) * Wv[k+3];
            }
            vsum += v;
        }
    }

    // ---- block reduction ----
#pragma unroll
    for (int off = 32; off > 0; off >>= 1)
        vsum += __shfl_down(vsum, off, 64);
    if ((tid & 63) == 0) wred[tid >> 6] = vsum;
    __syncthreads();
    if (tid == 0) {
        float t = 0.0f;
#pragma unroll
        for (int w = 0; w < TPB / 64; w++) t += wred[w];
        out[b] = t;
    }
}

extern "C" void kernel_launch(void* const* d_in, const int* in_sizes, int n_in,
                              void* d_out, int out_size, void* d_ws, size_t ws_size,
                              hipStream_t stream) {
    const float* x         = (const float*)d_in[0];
    const float* edge_attr = (const float*)d_in[2];
    const float* action    = (const float*)d_in[3];
    const int*   es        = (const int*)d_in[4];
    const int*   ed        = (const int*)d_in[5];
    const float* W1        = (const float*)d_in[6];
    const float* b1        = (const float*)d_in[7];
    const float* W2        = (const float*)d_in[8];
    const float* b2        = (const float*)d_in[9];
    const float* Wl        = (const float*)d_in[10];
    const float* bl        = (const float*)d_in[11];
    const float* Wv        = (const float*)d_in[12];
    const float* bv        = (const float*)d_in[13];
    float* out = (float*)d_out;

    critic_fused<<<dim3(out_size), dim3(TPB), 0, stream>>>(
        x, edge_attr, action, es, ed, W1, b1, W2, b2, Wl, bl, Wv, bv, out);
}

// Round 4
// 122.023 us; speedup vs baseline: 1.1467x; 1.0522x over previous
//
#include <hip/hip_runtime.h>

// Problem constants
#define NNODES 64
#define HID 32
#define NFACT 3
#define NE 1024
#define NROWS (NE + NFACT)   // 1027
#define TPB 512              // 8 waves/graph (R14). R15: (512,6) bounds -> no spill,
                             // occ 45%, dur unchanged vs TPB=256 => NOT occupancy-bound.
// R16/R17: packed-f16 conversion. Limiter is per-CU work volume (VALU ~48%, DS
// pipe ~50-60% by instr model, nothing saturated, occupancy-insensitive).
// Replace scalar fp32+bf16-repack math with v_pk_*_f16: stage B combine 14->4
// ops per 2 values and drops pack entirely (f16 MFMA eats the pairs); stage C
// stores P1/P2 as f16 pairs (cols k,k+16 in one u32) halving gathers, combine
// via pk_add/pk_fma/pk_max + v_dot2_f32_f16. f16 (11-bit mant) replaces bf16
// (8-bit) on the dominant error path -> absmax should not regress.
// R17 fix: cvt_pkrtz builtin returns __fp16x2, bit_cast to _Float16x2.
#define STR 36               // float row stride for xpp and fp32 scratch layout
#define QSTRH 20             // u32 row stride for packed-f16 Q rows (16 data + 4 pad)
#define MAXTILES 128         // 16-edge tile capacity (true max = 124)
#define EPT (NE / TPB)       // 2 edges cached per thread

typedef short bf16x8 __attribute__((ext_vector_type(8)));
typedef float f32x4  __attribute__((ext_vector_type(4)));
typedef float f32x16 __attribute__((ext_vector_type(16)));
typedef _Float16 f16x2 __attribute__((ext_vector_type(2)));
typedef _Float16 f16x8 __attribute__((ext_vector_type(8)));

// round-to-nearest-even two fp32 -> packed bf16x2 (lo | hi<<16)  [stage P MFMA]
__device__ __forceinline__ unsigned pack_bf2(float lo, float hi) {
    unsigned ul = __builtin_bit_cast(unsigned, lo);
    unsigned uh = __builtin_bit_cast(unsigned, hi);
    ul += 0x7fffu + ((ul >> 16) & 1u);
    uh += 0x7fffu + ((uh >> 16) & 1u);
    return (ul >> 16) | (uh & 0xffff0000u);
}
__device__ __forceinline__ short f2bf(float f) {
    unsigned u = __builtin_bit_cast(unsigned, f);
    u += 0x7fffu + ((u >> 16) & 1u);
    return (short)(u >> 16);
}
// fp32 pair -> packed f16 (RTZ, single v_cvt_pkrtz_f16_f32).
// Builtin returns __fp16-based vector; bit_cast bridges to _Float16-based.
__device__ __forceinline__ f16x2 pkrtz(float lo, float hi) {
    return __builtin_bit_cast(f16x2, __builtin_amdgcn_cvt_pkrtz(lo, hi));
}
// fp32 pair -> packed f16 (RNE, for weights)
__device__ __forceinline__ f16x2 packh2_rne(float lo, float hi) {
    f16x2 r; r.x = (_Float16)lo; r.y = (_Float16)hi; return r;
}
__device__ __forceinline__ float dot2acc(f16x2 a, f16x2 b, float c) {
#if __has_builtin(__builtin_amdgcn_fdot2)
    return __builtin_amdgcn_fdot2(a, b, c, false);
#else
    return c + (float)a.x * (float)b.x + (float)a.y * (float)b.y;
#endif
}
__device__ __forceinline__ float4 fma4(float a, float4 w, float4 c) {
    c.x = fmaf(a, w.x, c.x); c.y = fmaf(a, w.y, c.y);
    c.z = fmaf(a, w.z, c.z); c.w = fmaf(a, w.w, c.w);
    return c;
}

//   pep packed: low12 = edge id (0xFFF = pad), bits12-17 = dst, bits18-23 = src
__global__ __launch_bounds__(TPB, 6) void critic_fused(
    const float* __restrict__ x,
    const float* __restrict__ edge_attr,
    const float* __restrict__ action,
    const int*   __restrict__ es,
    const int*   __restrict__ ed,
    const float* __restrict__ W1,
    const float* __restrict__ b1,
    const float* __restrict__ W2,
    const float* __restrict__ b2,
    const float* __restrict__ Wl,
    const float* __restrict__ bl,
    const float* __restrict__ Wv,
    const float* __restrict__ bv,
    float* __restrict__ out)
{
    const int b    = blockIdx.x;
    const int tid  = threadIdx.x;
    const int lane = tid & 63;
    const int wv   = tid >> 6;          // 0..7
    const int quad = lane >> 4;
    const int m16  = lane & 15;
    const int kh   = quad * 8;
    const f16x2 z2 = { (_Float16)0.f, (_Float16)0.f };

    __shared__ __align__(16) float4 xs4[NNODES];
    __shared__ __align__(16) float  xpp[NNODES * STR];
    __shared__ __align__(16) float  qp0[NNODES * STR];   // f16 Q1 rows, then f16 P1 rows
    __shared__ __align__(16) float  qp1[NNODES * STR];   // f16 Q2 rows, then f16 P2 rows
    __shared__ __align__(16) float  W1s[10 * HID];
    __shared__ float  b1s[HID];
    __shared__ float  wred[TPB / 64];
    // CSR tables (built per block, 16-edge tiles)
    __shared__ int    sdeg[NNODES], soff[NNODES], scnt[NNODES];
    __shared__ int    tns[MAXTILES];
    __shared__ int    pep[MAXTILES * 16];
    __shared__ int    snt;

    unsigned* qh0 = (unsigned*)qp0;   // packed-f16 rows: stride QSTRH u32
    unsigned* qh1 = (unsigned*)qp1;

    // ---- Stage A: stage x + W1, zero xpp, init CSR tables ----
    if (tid < NNODES) { xs4[tid] = ((const float4*)x)[b * NNODES + tid]; sdeg[tid] = 0; scnt[tid] = 0; }
    if (tid < 80) ((float4*)W1s)[tid] = ((const float4*)W1)[tid];
    if (tid < HID) b1s[tid] = b1[tid];
    if (tid < MAXTILES) tns[tid] = 0;
#pragma unroll
    for (int i = 0; i < MAXTILES * 16 / TPB; i++) pep[tid + i * TPB] = 0xFFF;  // pad, node 0
    {   // vectorized xpp zero: 2304 floats = 576 float4 slots
        const float4 z4 = make_float4(0.f, 0.f, 0.f, 0.f);
#pragma unroll 1
        for (int i = tid; i < NNODES * STR / 4; i += TPB) ((float4*)xpp)[i] = z4;
    }

    // cache this thread's 2 edges in registers (coalesced global reads)
    int ces[EPT], ced[EPT];
#pragma unroll
    for (int i = 0; i < EPT; i++) {
        ces[i] = es[tid + i * TPB];
        ced[i] = ed[tid + i * TPB];
    }
    __syncthreads();

    // ---- CSR count + Stage Q (independent; co-scheduled to hide latency) ----
#pragma unroll
    for (int i = 0; i < EPT; i++) atomicAdd(&sdeg[ces[i]], 1);
    {
        // waves 0-3: Q1 (W1 rows 0-3 + b1), waves 4-7: Q2 (W1 rows 4-7)
        const int  n  = lane;
        const int  k0 = (wv & 3) * 8;
        const bool g1 = (wv < 4);
        const int  rb = g1 ? 0 : 4;
        const float4 xv = xs4[n];
        float4 qa, qb;
        if (g1) {
            const float4* b1v = (const float4*)&b1s[k0];
            qa = b1v[0]; qb = b1v[1];
        } else {
            qa = make_float4(0.f, 0.f, 0.f, 0.f); qb = qa;
        }
#pragma unroll 1
        for (int i = 0; i < 4; i++) {
            const float xi = (i == 0) ? xv.x : (i == 1) ? xv.y : (i == 2) ? xv.z : xv.w;
            const float4* wa = (const float4*)&W1s[(rb + i) * HID + k0];
            qa = fma4(xi, wa[0], qa); qb = fma4(xi, wa[1], qb);
        }
        uint4 p;   // pack 8 fp32 -> 4 u32 (f16 pairs), one b128 write
        p.x = __builtin_bit_cast(unsigned, pkrtz(qa.x, qa.y));
        p.y = __builtin_bit_cast(unsigned, pkrtz(qa.z, qa.w));
        p.z = __builtin_bit_cast(unsigned, pkrtz(qb.x, qb.y));
        p.w = __builtin_bit_cast(unsigned, pkrtz(qb.z, qb.w));
        unsigned* dst = g1 ? qh0 : qh1;
        *(uint4*)&dst[n * QSTRH + (wv & 3) * 4] = p;
    }
    __syncthreads();

    // ---- CSR scan (wave 0) + tile-node fill ----
    if (tid < NNODES) {
        const int cnt = (sdeg[tid] + 15) >> 4;
        int scan = cnt;
#pragma unroll
        for (int o = 1; o < 64; o <<= 1) {
            const int v = __shfl_up(scan, o);
            if (tid >= o) scan += v;
        }
        const int base = scan - cnt;
        soff[tid] = base;
        if (tid == NNODES - 1) snt = scan;           // ~90-96, <=124
#pragma unroll 1
        for (int j = 0; j < cnt; j++) tns[base + j] = tid;
    }
    __syncthreads();

    // ---- CSR scatter (cached edges) ----
#pragma unroll
    for (int i = 0; i < EPT; i++) {
        const int n = ces[i];
        const int idx = atomicAdd(&scnt[n], 1);
        pep[soff[n] * 16 + idx] = (tid + i * TPB) | (ced[i] << 12) | (n << 18);
    }
    __syncthreads();

    // ---- Stage B: pair-tiled f16-MFMA edge messages (32 edges / 2 nodes per iter) ----
    {
        const float2* ea2 = (const float2*)edge_attr + (size_t)b * NE;
        const int NW   = TPB / 64;             // 8 waves
        const int klo  = (lane >> 5) * 8;      // K-slice base (0 or 8)
        const int klo2 = klo >> 1;             // u32 offset of the slice
        const int n32  = lane & 31;

        // edge-attr weights as packed f16 pairs (cols klo+2j, klo+2j+1)
        f16x2 w8p[4], w8q[4], w9p[4], w9q[4];
#pragma unroll
        for (int j = 0; j < 4; j++) {
            w8p[j] = packh2_rne(W1s[8 * HID + klo + 2 * j],      W1s[8 * HID + klo + 2 * j + 1]);
            w8q[j] = packh2_rne(W1s[8 * HID + 16 + klo + 2 * j], W1s[8 * HID + 16 + klo + 2 * j + 1]);
            w9p[j] = packh2_rne(W1s[9 * HID + klo + 2 * j],      W1s[9 * HID + klo + 2 * j + 1]);
            w9q[j] = packh2_rne(W1s[9 * HID + 16 + klo + 2 * j], W1s[9 * HID + 16 + klo + 2 * j + 1]);
        }
        f16x8 hfA, hfB;   // W2 B-frags: B[k][n32], K-halves 0..15 / 16..31
#pragma unroll
        for (int j = 0; j < 8; j++) {
            hfA[j] = (_Float16)W2[(klo + j) * HID + n32];
            hfB[j] = (_Float16)W2[(16 + klo + j) * HID + n32];
        }

        const int np = (snt + 1) >> 1;

#pragma unroll 1
        for (int p = wv; p < np; p += NW) {
            const int raw = pep[p * 32 + n32];        // edge slot = window row n32
            const int tA  = tns[2 * p];
            const int tB  = tns[2 * p + 1];
            const int e    = raw & 0xFFF;
            const bool pad = (e == 0xFFF);
            const int d0   = (raw >> 12) & 63;
            const int nd   = (raw >> 18) & 63;        // src node of MY edge
            const float2 ea = ea2[pad ? 0 : e];

            // packed-f16 gathers: 4 x b128 total
            const uint4 A1 = *(const uint4*)&qh0[nd * QSTRH + klo2];
            const uint4 A2 = *(const uint4*)&qh0[nd * QSTRH + 8 + klo2];
            const uint4 G1 = *(const uint4*)&qh1[d0 * QSTRH + klo2];
            const uint4 G2 = *(const uint4*)&qh1[d0 * QSTRH + 8 + klo2];

            const f16x2 ex2 = pkrtz(ea.x, ea.x);
            const f16x2 ey2 = pkrtz(ea.y, ea.y);
            const unsigned pz = pad ? 0u : 0xFFFFFFFFu;

            uint4 pa4, pb4;
#define MSLOT(dst, au, gu, w8, w9) { \
            f16x2 t = __builtin_bit_cast(f16x2, au) + __builtin_bit_cast(f16x2, gu); \
            t = __builtin_elementwise_fma(ex2, w8, t); \
            t = __builtin_elementwise_fma(ey2, w9, t); \
            t = __builtin_elementwise_max(t, z2); \
            dst = __builtin_bit_cast(unsigned, t) & pz; }
            MSLOT(pa4.x, A1.x, G1.x, w8p[0], w9p[0])
            MSLOT(pa4.y, A1.y, G1.y, w8p[1], w9p[1])
            MSLOT(pa4.z, A1.z, G1.z, w8p[2], w9p[2])
            MSLOT(pa4.w, A1.w, G1.w, w8p[3], w9p[3])
            MSLOT(pb4.x, A2.x, G2.x, w8q[0], w9q[0])
            MSLOT(pb4.y, A2.y, G2.y, w8q[1], w9q[1])
            MSLOT(pb4.z, A2.z, G2.z, w8q[2], w9q[2])
            MSLOT(pb4.w, A2.w, G2.w, w8q[3], w9q[3])
#undef MSLOT
            const f16x8 afA = __builtin_bit_cast(f16x8, pa4);
            const f16x8 afB = __builtin_bit_cast(f16x8, pb4);

            f32x16 c;
#pragma unroll
            for (int j = 0; j < 16; j++) c[j] = 0.0f;
            c = __builtin_amdgcn_mfma_f32_32x32x16_f16(afA, hfA, c, 0, 0, 0);
            c = __builtin_amdgcn_mfma_f32_32x32x16_f16(afB, hfB, c, 0, 0, 0);

            // C: col=lane&31, row=(reg&3)+8*(reg>>2)+4*(lane>>5).
            // regs 0-7 -> rows 0-15 (tile A), regs 8-15 -> rows 16-31 (tile B).
            float sA = ((c[0] + c[1]) + (c[2] + c[3])) + ((c[4] + c[5]) + (c[6] + c[7]));
            float sB = ((c[8] + c[9]) + (c[10] + c[11])) + ((c[12] + c[13]) + (c[14] + c[15]));
            sA += __shfl_xor(sA, 32);
            sB += __shfl_xor(sB, 32);
            const int   nst = (lane < 32) ? tA : tB;
            const float sv  = (lane < 32) ? sA : sB;
            atomicAdd(&xpp[nst * STR + n32], sv);     // full wave, contiguous per node
        }
    }
    __syncthreads();

    // ---- Stage-P constants (loaded after B to keep stage-B VGPR peak low) ----
    // waves 0-3 produce P1 (Wl[0:36], +bl), waves 4-7 produce P2 (Wl[36:72])
    const bool g1p   = (wv < 4);
    const int  cbase = g1p ? 4 : 40;     // Wl row offset of the MFMA K=32 part
    const int  xbase = g1p ? 0 : 36;     // Wl row offset of the x-part (K=4 tail)
    bf16x8 bPa, bPb;                     // B-fragments, col halves
#pragma unroll
    for (int j = 0; j < 8; j++) {
        bPa[j] = f2bf(Wl[(cbase + kh + j) * HID + m16]);
        bPb[j] = f2bf(Wl[(cbase + kh + j) * HID + 16 + m16]);
    }
    float wxa[4], wxb[4];                // x-part weights
#pragma unroll
    for (int i = 0; i < 4; i++) {
        wxa[i] = Wl[(xbase + i) * HID + m16];
        wxb[i] = Wl[(xbase + i) * HID + 16 + m16];
    }
    const float bca = g1p ? bl[m16] : 0.f;
    const float bcb = g1p ? bl[16 + m16] : 0.f;
    float b2k[8];
#pragma unroll
    for (int j = 0; j < 8; j++) b2k[j] = b2[kh + j];
    const int   mrow = (wv & 3) * 16 + m16;          // A-row this lane owns in stage P
    const float dn   = (float)sdeg[mrow];

    // ---- Stage P: head projections via MFMA; outputs packed f16 (cols k,k+16) ----
    {
        const float4* xr = (const float4*)&xpp[mrow * STR + kh];
        float4 x0 = xr[0], x1 = xr[1];
        x0.x = fmaf(dn, b2k[0], x0.x); x0.y = fmaf(dn, b2k[1], x0.y);
        x0.z = fmaf(dn, b2k[2], x0.z); x0.w = fmaf(dn, b2k[3], x0.w);
        x1.x = fmaf(dn, b2k[4], x1.x); x1.y = fmaf(dn, b2k[5], x1.y);
        x1.z = fmaf(dn, b2k[6], x1.z); x1.w = fmaf(dn, b2k[7], x1.w);
        uint4 packed;
        packed.x = pack_bf2(x0.x, x0.y);
        packed.y = pack_bf2(x0.z, x0.w);
        packed.z = pack_bf2(x1.x, x1.y);
        packed.w = pack_bf2(x1.z, x1.w);
        const bf16x8 af = __builtin_bit_cast(bf16x8, packed);

        f32x4 ca, cb;
#pragma unroll
        for (int r = 0; r < 4; r++) {
            const float4 xv = xs4[(wv & 3) * 16 + quad * 4 + r];
            float a0 = bca, a1 = bcb;
#pragma unroll
            for (int i = 0; i < 4; i++) {
                const float xi = (i == 0) ? xv.x : (i == 1) ? xv.y : (i == 2) ? xv.z : xv.w;
                a0 = fmaf(xi, wxa[i], a0);
                a1 = fmaf(xi, wxb[i], a1);
            }
            ca[r] = a0; cb[r] = a1;
        }
        ca = __builtin_amdgcn_mfma_f32_16x16x32_bf16(af, bPa, ca, 0, 0, 0);
        cb = __builtin_amdgcn_mfma_f32_16x16x32_bf16(af, bPb, cb, 0, 0, 0);

        __syncthreads();   // Q-phase f16 reads fully drained before P overwrite
        // P row layout: u32 slot m16 of row holds f16 pair (col m16, col m16+16)
        unsigned* dsth = g1p ? qh0 : qh1;
#pragma unroll
        for (int r = 0; r < 4; r++) {
            const int row = (wv & 3) * 16 + quad * 4 + r;
            dsth[row * QSTRH + m16] = __builtin_bit_cast(unsigned, pkrtz(ca[r], cb[r]));
        }
    }
    __syncthreads();

    // ---- Stage C: per-row combine + value head (packed f16 + dot2) ----
    float vsum = 0.0f;
    {
        const float* actb = action + (size_t)b * NROWS;
        const float bvv = bv[0];
        const float* Wl72 = Wl + 72 * HID;
        // weights permuted to the (k, k+16) pair layout
        f16x2 wlh[16], wvh[16];
#pragma unroll
        for (int j = 0; j < 16; j++) {
            wlh[j] = packh2_rne(Wl72[j], Wl72[j + 16]);
            wvh[j] = packh2_rne(Wv[j],  Wv[j + 16]);
        }

#define CSLOT(j, pu, qu, acc) { \
        f16x2 t = __builtin_bit_cast(f16x2, pu) + __builtin_bit_cast(f16x2, qu); \
        t = __builtin_elementwise_fma(a2, wlh[j], t); \
        t = __builtin_elementwise_max(t, z2); \
        acc = dot2acc(t, wvh[j], acc); }

#pragma unroll 1
        for (int i = 0; i < EPT; i++) {
            const int na = ces[i], nb = ced[i];           // cached edge endpoints
            const float a = actb[tid + i * TPB];
            const unsigned* ra = &qh0[na * QSTRH];
            const unsigned* rb = &qh1[nb * QSTRH];
            const uint4 Pa0 = *(const uint4*)&ra[0];
            const uint4 Pa1 = *(const uint4*)&ra[4];
            const uint4 Pa2 = *(const uint4*)&ra[8];
            const uint4 Pa3 = *(const uint4*)&ra[12];
            const uint4 Pb0 = *(const uint4*)&rb[0];
            const uint4 Pb1 = *(const uint4*)&rb[4];
            const uint4 Pb2 = *(const uint4*)&rb[8];
            const uint4 Pb3 = *(const uint4*)&rb[12];
            const f16x2 a2 = pkrtz(a, a);
            float v0 = bvv, v1 = 0.0f;
            CSLOT( 0, Pa0.x, Pb0.x, v0) CSLOT( 1, Pa0.y, Pb0.y, v1)
            CSLOT( 2, Pa0.z, Pb0.z, v0) CSLOT( 3, Pa0.w, Pb0.w, v1)
            CSLOT( 4, Pa1.x, Pb1.x, v0) CSLOT( 5, Pa1.y, Pb1.y, v1)
            CSLOT( 6, Pa1.z, Pb1.z, v0) CSLOT( 7, Pa1.w, Pb1.w, v1)
            CSLOT( 8, Pa2.x, Pb2.x, v0) CSLOT( 9, Pa2.y, Pb2.y, v1)
            CSLOT(10, Pa2.z, Pb2.z, v0) CSLOT(11, Pa2.w, Pb2.w, v1)
            CSLOT(12, Pa3.x, Pb3.x, v0) CSLOT(13, Pa3.y, Pb3.y, v1)
            CSLOT(14, Pa3.z, Pb3.z, v0) CSLOT(15, Pa3.w, Pb3.w, v1)
            vsum += v0 + v1;
        }
        // factory rows 1024..1026 (na == nb)
        if (tid < NFACT) {
            const int r = NE + tid;
            const int na = NNODES - NFACT + tid;
            const float a = actb[r];
            const unsigned* ra = &qh0[na * QSTRH];
            const unsigned* rb = &qh1[na * QSTRH];
            const uint4 Pa0 = *(const uint4*)&ra[0];
            const uint4 Pa1 = *(const uint4*)&ra[4];
            const uint4 Pa2 = *(const uint4*)&ra[8];
            const uint4 Pa3 = *(const uint4*)&ra[12];
            const uint4 Pb0 = *(const uint4*)&rb[0];
            const uint4 Pb1 = *(const uint4*)&rb[4];
            const uint4 Pb2 = *(const uint4*)&rb[8];
            const uint4 Pb3 = *(const uint4*)&rb[12];
            const f16x2 a2 = pkrtz(a, a);
            float v0 = bvv, v1 = 0.0f;
            CSLOT( 0, Pa0.x, Pb0.x, v0) CSLOT( 1, Pa0.y, Pb0.y, v1)
            CSLOT( 2, Pa0.z, Pb0.z, v0) CSLOT( 3, Pa0.w, Pb0.w, v1)
            CSLOT( 4, Pa1.x, Pb1.x, v0) CSLOT( 5, Pa1.y, Pb1.y, v1)
            CSLOT( 6, Pa1.z, Pb1.z, v0) CSLOT( 7, Pa1.w, Pb1.w, v1)
            CSLOT( 8, Pa2.x, Pb2.x, v0) CSLOT( 9, Pa2.y, Pb2.y, v1)
            CSLOT(10, Pa2.z, Pb2.z, v0) CSLOT(11, Pa2.w, Pb2.w, v1)
            CSLOT(12, Pa3.x, Pb3.x, v0) CSLOT(13, Pa3.y, Pb3.y, v1)
            CSLOT(14, Pa3.z, Pb3.z, v0) CSLOT(15, Pa3.w, Pb3.w, v1)
            vsum += v0 + v1;
        }
#undef CSLOT
    }

    // ---- block reduction ----
#pragma unroll
    for (int off = 32; off > 0; off >>= 1)
        vsum += __shfl_down(vsum, off, 64);
    if ((tid & 63) == 0) wred[tid >> 6] = vsum;
    __syncthreads();
    if (tid == 0) {
        float t = 0.0f;
#pragma unroll
        for (int w = 0; w < TPB / 64; w++) t += wred[w];
        out[b] = t;
    }
}

extern "C" void kernel_launch(void* const* d_in, const int* in_sizes, int n_in,
                              void* d_out, int out_size, void* d_ws, size_t ws_size,
                              hipStream_t stream) {
    const float* x         = (const float*)d_in[0];
    const float* edge_attr = (const float*)d_in[2];
    const float* action    = (const float*)d_in[3];
    const int*   es        = (const int*)d_in[4];
    const int*   ed        = (const int*)d_in[5];
    const float* W1        = (const float*)d_in[6];
    const float* b1        = (const float*)d_in[7];
    const float* W2        = (const float*)d_in[8];
    const float* b2        = (const float*)d_in[9];
    const float* Wl        = (const float*)d_in[10];
    const float* bl        = (const float*)d_in[11];
    const float* Wv        = (const float*)d_in[12];
    const float* bv        = (const float*)d_in[13];
    float* out = (float*)d_out;

    critic_fused<<<dim3(out_size), dim3(TPB), 0, stream>>>(
        x, edge_attr, action, es, ed, W1, b1, W2, b2, Wl, bl, Wv, bv, out);
}

// Round 5
// 120.371 us; speedup vs baseline: 1.1625x; 1.0137x over previous
//
#include <hip/hip_runtime.h>

// Problem constants
#define NNODES 64
#define HID 32
#define NFACT 3
#define NE 1024
#define NROWS (NE + NFACT)   // 1027
#define TPB 512              // 8 waves/graph (R14); (512,6) bounds: no spill (R15)
// R18: CSR hoisted to a 1-block pre-kernel (edge list is graph-invariant; all
// 1024 blocks were rebuilding identical tables: LDS atomics + wave-0-only scan
// + 2 barriers each). Main kernel reads sdeg/snt/tns/pep from d_ws (L2-hot,
// ~10KB shared). Freed 9.4KB LDS now stages edge_attr (coalesced float4 in
// stage A) removing cold-HBM scatter loads from stage B's dependent chain;
// stage B also software-pipelines pep/tns one iteration ahead.
#define STR 36               // float row stride for xpp
#define QSTRH 20             // u32 row stride for packed-f16 Q rows (16 data + 4 pad)
#define MAXTILES 128         // 16-edge tile capacity (true max = 124)
#define EPT (NE / TPB)       // 2 edges cached per thread

typedef short bf16x8 __attribute__((ext_vector_type(8)));
typedef float f32x4  __attribute__((ext_vector_type(4)));
typedef float f32x16 __attribute__((ext_vector_type(16)));
typedef _Float16 f16x2 __attribute__((ext_vector_type(2)));
typedef _Float16 f16x8 __attribute__((ext_vector_type(8)));

// round-to-nearest-even two fp32 -> packed bf16x2 (lo | hi<<16)  [stage P MFMA]
__device__ __forceinline__ unsigned pack_bf2(float lo, float hi) {
    unsigned ul = __builtin_bit_cast(unsigned, lo);
    unsigned uh = __builtin_bit_cast(unsigned, hi);
    ul += 0x7fffu + ((ul >> 16) & 1u);
    uh += 0x7fffu + ((uh >> 16) & 1u);
    return (ul >> 16) | (uh & 0xffff0000u);
}
__device__ __forceinline__ short f2bf(float f) {
    unsigned u = __builtin_bit_cast(unsigned, f);
    u += 0x7fffu + ((u >> 16) & 1u);
    return (short)(u >> 16);
}
// fp32 pair -> packed f16 (RTZ, single v_cvt_pkrtz_f16_f32)
__device__ __forceinline__ f16x2 pkrtz(float lo, float hi) {
    return __builtin_bit_cast(f16x2, __builtin_amdgcn_cvt_pkrtz(lo, hi));
}
// fp32 pair -> packed f16 (RNE, for weights)
__device__ __forceinline__ f16x2 packh2_rne(float lo, float hi) {
    f16x2 r; r.x = (_Float16)lo; r.y = (_Float16)hi; return r;
}
__device__ __forceinline__ float dot2acc(f16x2 a, f16x2 b, float c) {
#if __has_builtin(__builtin_amdgcn_fdot2)
    return __builtin_amdgcn_fdot2(a, b, c, false);
#else
    return c + (float)a.x * (float)b.x + (float)a.y * (float)b.y;
#endif
}
__device__ __forceinline__ float4 fma4(float a, float4 w, float4 c) {
    c.x = fmaf(a, w.x, c.x); c.y = fmaf(a, w.y, c.y);
    c.z = fmaf(a, w.z, c.z); c.w = fmaf(a, w.w, c.w);
    return c;
}

// ---- CSR pre-kernel: 1 block builds the shared edge tiling into d_ws ----
// gws layout (ints): [0:64) sdeg | [64:128) soff | [128] snt | [256:384) tns
//                    | [512:2560) pep
//   pep packed: low12 = edge id (0xFFF = pad), bits12-17 = dst, bits18-23 = src
__global__ __launch_bounds__(256) void csr_build(
    const int* __restrict__ es, const int* __restrict__ ed, int* __restrict__ gws)
{
    const int tid = threadIdx.x;
    __shared__ int sdeg[NNODES], soff[NNODES], scnt[NNODES];
    __shared__ int tns[MAXTILES], snt;
    __shared__ int pep[MAXTILES * 16];
    if (tid < NNODES) { sdeg[tid] = 0; scnt[tid] = 0; }
    if (tid < MAXTILES) tns[tid] = 0;
#pragma unroll
    for (int i = tid; i < MAXTILES * 16; i += 256) pep[i] = 0xFFF;
    int ces[4], ced[4];
#pragma unroll
    for (int i = 0; i < 4; i++) { ces[i] = es[tid + i * 256]; ced[i] = ed[tid + i * 256]; }
    __syncthreads();
#pragma unroll
    for (int i = 0; i < 4; i++) atomicAdd(&sdeg[ces[i]], 1);
    __syncthreads();
    if (tid < NNODES) {          // wave 0 scan
        const int cnt = (sdeg[tid] + 15) >> 4;
        int scan = cnt;
#pragma unroll
        for (int o = 1; o < 64; o <<= 1) {
            const int v = __shfl_up(scan, o);
            if (tid >= o) scan += v;
        }
        const int base = scan - cnt;
        soff[tid] = base;
        if (tid == NNODES - 1) snt = scan;
#pragma unroll 1
        for (int j = 0; j < cnt; j++) tns[base + j] = tid;
    }
    __syncthreads();
#pragma unroll
    for (int i = 0; i < 4; i++) {
        const int n = ces[i];
        const int idx = atomicAdd(&scnt[n], 1);
        pep[soff[n] * 16 + idx] = (tid + i * 256) | (ced[i] << 12) | (n << 18);
    }
    __syncthreads();
    if (tid < NNODES) { gws[tid] = sdeg[tid]; gws[64 + tid] = soff[tid]; }
    if (tid == 0) gws[128] = snt;
    if (tid < MAXTILES) gws[256 + tid] = tns[tid];
#pragma unroll
    for (int i = tid; i < MAXTILES * 16; i += 256) gws[512 + i] = pep[i];
}

__global__ __launch_bounds__(TPB, 6) void critic_fused(
    const float* __restrict__ x,
    const float* __restrict__ edge_attr,
    const float* __restrict__ action,
    const int*   __restrict__ es,
    const int*   __restrict__ ed,
    const float* __restrict__ W1,
    const float* __restrict__ b1,
    const float* __restrict__ W2,
    const float* __restrict__ b2,
    const float* __restrict__ Wl,
    const float* __restrict__ bl,
    const float* __restrict__ Wv,
    const float* __restrict__ bv,
    const int*   __restrict__ gws,
    float* __restrict__ out)
{
    const int b    = blockIdx.x;
    const int tid  = threadIdx.x;
    const int lane = tid & 63;
    const int wv   = tid >> 6;          // 0..7
    const int quad = lane >> 4;
    const int m16  = lane & 15;
    const int kh   = quad * 8;
    const f16x2 z2 = { (_Float16)0.f, (_Float16)0.f };

    __shared__ __align__(16) float4 xs4[NNODES];
    __shared__ __align__(16) float  xpp[NNODES * STR];
    __shared__ __align__(16) float  qp0[NNODES * STR];   // f16 Q1 rows, then f16 P1 rows
    __shared__ __align__(16) float  qp1[NNODES * STR];   // f16 Q2 rows, then f16 P2 rows
    __shared__ __align__(16) float  W1s[10 * HID];
    __shared__ __align__(16) float  eas[NE * 2];         // staged edge_attr (8KB)
    __shared__ float  b1s[HID];
    __shared__ float  wred[TPB / 64];

    unsigned* qh0 = (unsigned*)qp0;   // packed-f16 rows: stride QSTRH u32
    unsigned* qh1 = (unsigned*)qp1;

    // ---- Stage A: stage x + W1 + edge_attr, zero xpp ----
    if (tid < NNODES) xs4[tid] = ((const float4*)x)[b * NNODES + tid];
    if (tid < 80) ((float4*)W1s)[tid] = ((const float4*)W1)[tid];
    if (tid < HID) b1s[tid] = b1[tid];
    ((float4*)eas)[tid] = ((const float4*)edge_attr)[(size_t)b * (NE / 2) + tid]; // 512 f4
    {   // vectorized xpp zero: 2304 floats = 576 float4 slots
        const float4 z4 = make_float4(0.f, 0.f, 0.f, 0.f);
#pragma unroll 1
        for (int i = tid; i < NNODES * STR / 4; i += TPB) ((float4*)xpp)[i] = z4;
    }

    // cache this thread's 2 edges in registers (coalesced; used in stage C)
    int ces[EPT], ced[EPT];
#pragma unroll
    for (int i = 0; i < EPT; i++) {
        ces[i] = es[tid + i * TPB];
        ced[i] = ed[tid + i * TPB];
    }
    __syncthreads();

    // ---- Stage Q: waves 0-3: Q1 (W1 rows 0-3 + b1), waves 4-7: Q2 (rows 4-7) ----
    {
        const int  n  = lane;
        const int  k0 = (wv & 3) * 8;
        const bool g1 = (wv < 4);
        const int  rb = g1 ? 0 : 4;
        const float4 xv = xs4[n];
        float4 qa, qb;
        if (g1) {
            const float4* b1v = (const float4*)&b1s[k0];
            qa = b1v[0]; qb = b1v[1];
        } else {
            qa = make_float4(0.f, 0.f, 0.f, 0.f); qb = qa;
        }
#pragma unroll 1
        for (int i = 0; i < 4; i++) {
            const float xi = (i == 0) ? xv.x : (i == 1) ? xv.y : (i == 2) ? xv.z : xv.w;
            const float4* wa = (const float4*)&W1s[(rb + i) * HID + k0];
            qa = fma4(xi, wa[0], qa); qb = fma4(xi, wa[1], qb);
        }
        uint4 p;   // pack 8 fp32 -> 4 u32 (f16 pairs), one b128 write
        p.x = __builtin_bit_cast(unsigned, pkrtz(qa.x, qa.y));
        p.y = __builtin_bit_cast(unsigned, pkrtz(qa.z, qa.w));
        p.z = __builtin_bit_cast(unsigned, pkrtz(qb.x, qb.y));
        p.w = __builtin_bit_cast(unsigned, pkrtz(qb.z, qb.w));
        unsigned* dst = g1 ? qh0 : qh1;
        *(uint4*)&dst[n * QSTRH + (wv & 3) * 4] = p;
    }
    __syncthreads();

    // ---- Stage B: pair-tiled f16-MFMA edge messages, pep/tns prefetched ----
    {
        const int* gtns = gws + 256;
        const int* gpep = gws + 512;
        const int NW   = TPB / 64;             // 8 waves
        const int klo  = (lane >> 5) * 8;      // K-slice base (0 or 8)
        const int klo2 = klo >> 1;             // u32 offset of the slice
        const int n32  = lane & 31;

        // edge-attr weights as packed f16 pairs (cols klo+2j, klo+2j+1)
        f16x2 w8p[4], w8q[4], w9p[4], w9q[4];
#pragma unroll
        for (int j = 0; j < 4; j++) {
            w8p[j] = packh2_rne(W1s[8 * HID + klo + 2 * j],      W1s[8 * HID + klo + 2 * j + 1]);
            w8q[j] = packh2_rne(W1s[8 * HID + 16 + klo + 2 * j], W1s[8 * HID + 16 + klo + 2 * j + 1]);
            w9p[j] = packh2_rne(W1s[9 * HID + klo + 2 * j],      W1s[9 * HID + klo + 2 * j + 1]);
            w9q[j] = packh2_rne(W1s[9 * HID + 16 + klo + 2 * j], W1s[9 * HID + 16 + klo + 2 * j + 1]);
        }
        f16x8 hfA, hfB;   // W2 B-frags: B[k][n32], K-halves 0..15 / 16..31
#pragma unroll
        for (int j = 0; j < 8; j++) {
            hfA[j] = (_Float16)W2[(klo + j) * HID + n32];
            hfB[j] = (_Float16)W2[(16 + klo + j) * HID + n32];
        }

        const int np = (gws[128] + 1) >> 1;

        int p = wv;
        int raw = 0xFFF, tA = 0, tB = 0;
        if (p < np) {
            raw = gpep[p * 32 + n32];
            const int2 tt = *(const int2*)&gtns[2 * p];
            tA = tt.x; tB = tt.y;
        }
#pragma unroll 1
        while (p < np) {
            const int pn = p + NW;
            int rawn = 0xFFF, tAn = 0, tBn = 0;
            if (pn < np) {                       // prefetch next iter (L2-hot)
                rawn = gpep[pn * 32 + n32];
                const int2 ttn = *(const int2*)&gtns[2 * pn];
                tAn = ttn.x; tBn = ttn.y;
            }
            const int e    = raw & 0xFFF;
            const bool pad = (e == 0xFFF);
            const int d0   = (raw >> 12) & 63;
            const int nd   = (raw >> 18) & 63;
            const float2 ea = *(const float2*)&eas[(pad ? 0 : e) * 2];   // LDS

            // packed-f16 gathers: 4 x b128 total
            const uint4 A1 = *(const uint4*)&qh0[nd * QSTRH + klo2];
            const uint4 A2 = *(const uint4*)&qh0[nd * QSTRH + 8 + klo2];
            const uint4 G1 = *(const uint4*)&qh1[d0 * QSTRH + klo2];
            const uint4 G2 = *(const uint4*)&qh1[d0 * QSTRH + 8 + klo2];

            const f16x2 ex2 = pkrtz(ea.x, ea.x);
            const f16x2 ey2 = pkrtz(ea.y, ea.y);
            const unsigned pz = pad ? 0u : 0xFFFFFFFFu;

            uint4 pa4, pb4;
#define MSLOT(dst, au, gu, w8, w9) { \
            f16x2 t = __builtin_bit_cast(f16x2, au) + __builtin_bit_cast(f16x2, gu); \
            t = __builtin_elementwise_fma(ex2, w8, t); \
            t = __builtin_elementwise_fma(ey2, w9, t); \
            t = __builtin_elementwise_max(t, z2); \
            dst = __builtin_bit_cast(unsigned, t) & pz; }
            MSLOT(pa4.x, A1.x, G1.x, w8p[0], w9p[0])
            MSLOT(pa4.y, A1.y, G1.y, w8p[1], w9p[1])
            MSLOT(pa4.z, A1.z, G1.z, w8p[2], w9p[2])
            MSLOT(pa4.w, A1.w, G1.w, w8p[3], w9p[3])
            MSLOT(pb4.x, A2.x, G2.x, w8q[0], w9q[0])
            MSLOT(pb4.y, A2.y, G2.y, w8q[1], w9q[1])
            MSLOT(pb4.z, A2.z, G2.z, w8q[2], w9q[2])
            MSLOT(pb4.w, A2.w, G2.w, w8q[3], w9q[3])
#undef MSLOT
            const f16x8 afA = __builtin_bit_cast(f16x8, pa4);
            const f16x8 afB = __builtin_bit_cast(f16x8, pb4);

            f32x16 c;
#pragma unroll
            for (int j = 0; j < 16; j++) c[j] = 0.0f;
            c = __builtin_amdgcn_mfma_f32_32x32x16_f16(afA, hfA, c, 0, 0, 0);
            c = __builtin_amdgcn_mfma_f32_32x32x16_f16(afB, hfB, c, 0, 0, 0);

            // C: col=lane&31, row=(reg&3)+8*(reg>>2)+4*(lane>>5).
            float sA = ((c[0] + c[1]) + (c[2] + c[3])) + ((c[4] + c[5]) + (c[6] + c[7]));
            float sB = ((c[8] + c[9]) + (c[10] + c[11])) + ((c[12] + c[13]) + (c[14] + c[15]));
            sA += __shfl_xor(sA, 32);
            sB += __shfl_xor(sB, 32);
            const int   nst = (lane < 32) ? tA : tB;
            const float sv  = (lane < 32) ? sA : sB;
            atomicAdd(&xpp[nst * STR + n32], sv);

            p = pn; raw = rawn; tA = tAn; tB = tBn;
        }
    }
    __syncthreads();

    // ---- Stage-P constants ----
    // waves 0-3 produce P1 (Wl[0:36], +bl), waves 4-7 produce P2 (Wl[36:72])
    const bool g1p   = (wv < 4);
    const int  cbase = g1p ? 4 : 40;
    const int  xbase = g1p ? 0 : 36;
    bf16x8 bPa, bPb;
#pragma unroll
    for (int j = 0; j < 8; j++) {
        bPa[j] = f2bf(Wl[(cbase + kh + j) * HID + m16]);
        bPb[j] = f2bf(Wl[(cbase + kh + j) * HID + 16 + m16]);
    }
    float wxa[4], wxb[4];
#pragma unroll
    for (int i = 0; i < 4; i++) {
        wxa[i] = Wl[(xbase + i) * HID + m16];
        wxb[i] = Wl[(xbase + i) * HID + 16 + m16];
    }
    const float bca = g1p ? bl[m16] : 0.f;
    const float bcb = g1p ? bl[16 + m16] : 0.f;
    float b2k[8];
#pragma unroll
    for (int j = 0; j < 8; j++) b2k[j] = b2[kh + j];
    const int   mrow = (wv & 3) * 16 + m16;
    const float dn   = (float)gws[mrow];        // degree from pre-kernel

    // ---- Stage P: head projections via MFMA; outputs packed f16 (cols k,k+16) ----
    {
        const float4* xr = (const float4*)&xpp[mrow * STR + kh];
        float4 x0 = xr[0], x1 = xr[1];
        x0.x = fmaf(dn, b2k[0], x0.x); x0.y = fmaf(dn, b2k[1], x0.y);
        x0.z = fmaf(dn, b2k[2], x0.z); x0.w = fmaf(dn, b2k[3], x0.w);
        x1.x = fmaf(dn, b2k[4], x1.x); x1.y = fmaf(dn, b2k[5], x1.y);
        x1.z = fmaf(dn, b2k[6], x1.z); x1.w = fmaf(dn, b2k[7], x1.w);
        uint4 packed;
        packed.x = pack_bf2(x0.x, x0.y);
        packed.y = pack_bf2(x0.z, x0.w);
        packed.z = pack_bf2(x1.x, x1.y);
        packed.w = pack_bf2(x1.z, x1.w);
        const bf16x8 af = __builtin_bit_cast(bf16x8, packed);

        f32x4 ca, cb;
#pragma unroll
        for (int r = 0; r < 4; r++) {
            const float4 xv = xs4[(wv & 3) * 16 + quad * 4 + r];
            float a0 = bca, a1 = bcb;
#pragma unroll
            for (int i = 0; i < 4; i++) {
                const float xi = (i == 0) ? xv.x : (i == 1) ? xv.y : (i == 2) ? xv.z : xv.w;
                a0 = fmaf(xi, wxa[i], a0);
                a1 = fmaf(xi, wxb[i], a1);
            }
            ca[r] = a0; cb[r] = a1;
        }
        ca = __builtin_amdgcn_mfma_f32_16x16x32_bf16(af, bPa, ca, 0, 0, 0);
        cb = __builtin_amdgcn_mfma_f32_16x16x32_bf16(af, bPb, cb, 0, 0, 0);

        __syncthreads();   // Q-phase f16 reads fully drained before P overwrite
        unsigned* dsth = g1p ? qh0 : qh1;
#pragma unroll
        for (int r = 0; r < 4; r++) {
            const int row = (wv & 3) * 16 + quad * 4 + r;
            dsth[row * QSTRH + m16] = __builtin_bit_cast(unsigned, pkrtz(ca[r], cb[r]));
        }
    }
    __syncthreads();

    // ---- Stage C: per-row combine + value head (packed f16 + dot2) ----
    float vsum = 0.0f;
    {
        const float* actb = action + (size_t)b * NROWS;
        const float bvv = bv[0];
        const float* Wl72 = Wl + 72 * HID;
        f16x2 wlh[16], wvh[16];
#pragma unroll
        for (int j = 0; j < 16; j++) {
            wlh[j] = packh2_rne(Wl72[j], Wl72[j + 16]);
            wvh[j] = packh2_rne(Wv[j],  Wv[j + 16]);
        }

#define CSLOT(j, pu, qu, acc) { \
        f16x2 t = __builtin_bit_cast(f16x2, pu) + __builtin_bit_cast(f16x2, qu); \
        t = __builtin_elementwise_fma(a2, wlh[j], t); \
        t = __builtin_elementwise_max(t, z2); \
        acc = dot2acc(t, wvh[j], acc); }

#pragma unroll 1
        for (int i = 0; i < EPT; i++) {
            const int na = ces[i], nb = ced[i];
            const float a = actb[tid + i * TPB];
            const unsigned* ra = &qh0[na * QSTRH];
            const unsigned* rb = &qh1[nb * QSTRH];
            const uint4 Pa0 = *(const uint4*)&ra[0];
            const uint4 Pa1 = *(const uint4*)&ra[4];
            const uint4 Pa2 = *(const uint4*)&ra[8];
            const uint4 Pa3 = *(const uint4*)&ra[12];
            const uint4 Pb0 = *(const uint4*)&rb[0];
            const uint4 Pb1 = *(const uint4*)&rb[4];
            const uint4 Pb2 = *(const uint4*)&rb[8];
            const uint4 Pb3 = *(const uint4*)&rb[12];
            const f16x2 a2 = pkrtz(a, a);
            float v0 = bvv, v1 = 0.0f;
            CSLOT( 0, Pa0.x, Pb0.x, v0) CSLOT( 1, Pa0.y, Pb0.y, v1)
            CSLOT( 2, Pa0.z, Pb0.z, v0) CSLOT( 3, Pa0.w, Pb0.w, v1)
            CSLOT( 4, Pa1.x, Pb1.x, v0) CSLOT( 5, Pa1.y, Pb1.y, v1)
            CSLOT( 6, Pa1.z, Pb1.z, v0) CSLOT( 7, Pa1.w, Pb1.w, v1)
            CSLOT( 8, Pa2.x, Pb2.x, v0) CSLOT( 9, Pa2.y, Pb2.y, v1)
            CSLOT(10, Pa2.z, Pb2.z, v0) CSLOT(11, Pa2.w, Pb2.w, v1)
            CSLOT(12, Pa3.x, Pb3.x, v0) CSLOT(13, Pa3.y, Pb3.y, v1)
            CSLOT(14, Pa3.z, Pb3.z, v0) CSLOT(15, Pa3.w, Pb3.w, v1)
            vsum += v0 + v1;
        }
        // factory rows 1024..1026 (na == nb)
        if (tid < NFACT) {
            const int r = NE + tid;
            const int na = NNODES - NFACT + tid;
            const float a = actb[r];
            const unsigned* ra = &qh0[na * QSTRH];
            const unsigned* rb = &qh1[na * QSTRH];
            const uint4 Pa0 = *(const uint4*)&ra[0];
            const uint4 Pa1 = *(const uint4*)&ra[4];
            const uint4 Pa2 = *(const uint4*)&ra[8];
            const uint4 Pa3 = *(const uint4*)&ra[12];
            const uint4 Pb0 = *(const uint4*)&rb[0];
            const uint4 Pb1 = *(const uint4*)&rb[4];
            const uint4 Pb2 = *(const uint4*)&rb[8];
            const uint4 Pb3 = *(const uint4*)&rb[12];
            const f16x2 a2 = pkrtz(a, a);
            float v0 = bvv, v1 = 0.0f;
            CSLOT( 0, Pa0.x, Pb0.x, v0) CSLOT( 1, Pa0.y, Pb0.y, v1)
            CSLOT( 2, Pa0.z, Pb0.z, v0) CSLOT( 3, Pa0.w, Pb0.w, v1)
            CSLOT( 4, Pa1.x, Pb1.x, v0) CSLOT( 5, Pa1.y, Pb1.y, v1)
            CSLOT( 6, Pa1.z, Pb1.z, v0) CSLOT( 7, Pa1.w, Pb1.w, v1)
            CSLOT( 8, Pa2.x, Pb2.x, v0) CSLOT( 9, Pa2.y, Pb2.y, v1)
            CSLOT(10, Pa2.z, Pb2.z, v0) CSLOT(11, Pa2.w, Pb2.w, v1)
            CSLOT(12, Pa3.x, Pb3.x, v0) CSLOT(13, Pa3.y, Pb3.y, v1)
            CSLOT(14, Pa3.z, Pb3.z, v0) CSLOT(15, Pa3.w, Pb3.w, v1)
            vsum += v0 + v1;
        }
#undef CSLOT
    }

    // ---- block reduction ----
#pragma unroll
    for (int off = 32; off > 0; off >>= 1)
        vsum += __shfl_down(vsum, off, 64);
    if ((tid & 63) == 0) wred[tid >> 6] = vsum;
    __syncthreads();
    if (tid == 0) {
        float t = 0.0f;
#pragma unroll
        for (int w = 0; w < TPB / 64; w++) t += wred[w];
        out[b] = t;
    }
}

extern "C" void kernel_launch(void* const* d_in, const int* in_sizes, int n_in,
                              void* d_out, int out_size, void* d_ws, size_t ws_size,
                              hipStream_t stream) {
    const float* x         = (const float*)d_in[0];
    const float* edge_attr = (const float*)d_in[2];
    const float* action    = (const float*)d_in[3];
    const int*   es        = (const int*)d_in[4];
    const int*   ed        = (const int*)d_in[5];
    const float* W1        = (const float*)d_in[6];
    const float* b1        = (const float*)d_in[7];
    const float* W2        = (const float*)d_in[8];
    const float* b2        = (const float*)d_in[9];
    const float* Wl        = (const float*)d_in[10];
    const float* bl        = (const float*)d_in[11];
    const float* Wv        = (const float*)d_in[12];
    const float* bv        = (const float*)d_in[13];
    float* out = (float*)d_out;
    int*   gws = (int*)d_ws;   // needs 2560 ints = 10.2KB

    csr_build<<<dim3(1), dim3(256), 0, stream>>>(es, ed, gws);
    critic_fused<<<dim3(out_size), dim3(TPB), 0, stream>>>(
        x, edge_attr, action, es, ed, W1, b1, W2, b2, Wl, bl, Wv, bv, gws, out);
}